// Round 3
// baseline (179.165 us; speedup 1.0000x reference)
//
#include <hip/hip_runtime.h>
#include <cstdint>
#include <cstddef>

#define EPS 1e-5f

typedef float    f4    __attribute__((ext_vector_type(4)));
typedef _Float16 half8 __attribute__((ext_vector_type(8)));

#define S_XS 33
#define LOG2E 1.44269504088896f

// raw-rate transcendentals (v_exp_f32 / v_rcp_f32 / v_rsq_f32)
__device__ __forceinline__ float fexp(float x)  { return __builtin_amdgcn_exp2f(x * LOG2E); }
__device__ __forceinline__ float frcp(float x)  { return __builtin_amdgcn_rcpf(x); }
__device__ __forceinline__ float frsq(float x)  { return __builtin_amdgcn_rsqf(x); }
__device__ __forceinline__ float fsig(float g)  { return frcp(1.f + __builtin_amdgcn_exp2f(g * -LOG2E)); }
__device__ __forceinline__ float felu(float t)  { return t > 0.f ? t : fexp(t) - 1.f; }

// ---- K_prep: conv (0..511) + weight-GRN (512..767) + out-zero (768..783) ----
// UNCHANGED from the proven 164.5 µs version.
__global__ __launch_bounds__(256) void k_prep(
    const float* __restrict__ in_w2, _Float16* __restrict__ w2c,
    const float* __restrict__ x, const float* __restrict__ w1,
    const float* __restrict__ b1, const float* __restrict__ w2,
    const float* __restrict__ b2, const float* __restrict__ lng,
    const float* __restrict__ lnb,
    float* __restrict__ x_t, float* __restrict__ wts_t,
    float* __restrict__ outp)
{
    __shared__ float w1s[32 * S_XS];
    __shared__ float w2s[64 * S_XS];
    __shared__ float xsW[32 * S_XS];
    __shared__ float ytile[32 * S_XS];

    const int bid = blockIdx.x;
    const int tid = threadIdx.x;

    if (bid < 512) {   // ---- conv path ----
        int t = bid * 256 + tid;
        int q  = t & 3;
        int g  = (t >> 2) & 255;
        int fk = t >> 10;                   // f*4 + kq
        int f = fk >> 2, kq = fk & 3;
        const float* ip = in_w2 + ((size_t)f * 256 + g) * 128 + kq * 32 + q * 8;
        f4 v0 = *(const f4*)ip, v1 = *(const f4*)(ip + 4);
        half8 h;
        #pragma unroll
        for (int i = 0; i < 4; ++i) { h[i] = (_Float16)v0[i]; h[4 + i] = (_Float16)v1[i]; }
        *(half8*)(w2c + (size_t)fk * 8192 + q * 2048 + g * 8) = h;
        return;
    }

    if (bid >= 768) {  // ---- out-zero path (replaces memset launch) ----
        int t = (bid - 768) * 256 + tid;
        f4 z; z[0] = 0.f; z[1] = 0.f; z[2] = 0.f; z[3] = 0.f;
        for (int i = t; i < 262144; i += 4096)
            *(f4*)(outp + (size_t)i * 4) = z;
        return;
    }

    // ---- weight-GRN path ----
    const int lane = tid & 63;
    const int f = lane & 31;
    const int wv = tid >> 6;
    const int row0 = (bid - 512) * 32;

    for (int i = tid; i < 1024; i += 256) {
        int r = i >> 5, c = i & 31;
        w1s[r * S_XS + c] = w1[i];
        xsW[r * S_XS + c] = x[(size_t)row0 * 32 + i];
    }
    for (int i = tid; i < 2048; i += 256) {
        int r = i >> 5, c = i & 31;
        w2s[r * S_XS + c] = w2[i];
    }
    const float b1f = b1[f], b2a = b2[f], b2g = b2[f + 32];
    const float lgf = lng[f], lbf = lnb[f];
    __syncthreads();

    for (int rr = 0; rr < 8; ++rr) {
        const int r = wv * 8 + rr;
        float acc = b1f;
        #pragma unroll
        for (int k = 0; k < 32; ++k)
            acc = fmaf(w1s[f * S_XS + k], xsW[r * S_XS + k], acc);
        float hval = felu(acc);

        float a = b2a, g = b2g;
        #pragma unroll
        for (int k = 0; k < 32; ++k) {
            float hk = __shfl(hval, k, 64);
            a = fmaf(w2s[f * S_XS + k], hk, a);
            g = fmaf(w2s[(f + 32) * S_XS + k], hk, g);
        }
        float xv = xsW[r * S_XS + f];
        float v = xv + a * fsig(g);

        float s = v;
        #pragma unroll
        for (int o = 1; o < 64; o <<= 1) s += __shfl_xor(s, o, 64);
        float mu = s * (1.f / 64.f);
        float d = v - mu;
        float sq = d * d;
        #pragma unroll
        for (int o = 1; o < 64; o <<= 1) sq += __shfl_xor(sq, o, 64);
        float y = d * frsq(sq * (1.f / 64.f) + EPS) * lgf + lbf;

        float m = y;
        #pragma unroll
        for (int o = 1; o < 64; o <<= 1) m = fmaxf(m, __shfl_xor(m, o, 64));
        float e = fexp(y - m);
        float se = e;
        #pragma unroll
        for (int o = 1; o < 64; o <<= 1) se += __shfl_xor(se, o, 64);
        if (lane < 32) ytile[r * S_XS + f] = e * 2.f * frcp(se);
    }
    __syncthreads();
    for (int i = tid; i < 1024; i += 256) {
        int ff = i >> 5, r = i & 31;
        x_t[(size_t)ff * 8192 + row0 + r]   = xsW[r * S_XS + ff];
        wts_t[(size_t)ff * 8192 + row0 + r] = ytile[r * S_XS + ff];
    }
}

// ---------------- K_main v3: barrier-free K-loop, B direct from L2 ----------
// Post-mortem r1: counted-vmcnt ring REGRESSED (66.5->85us) -> stage latency
// was never the stall. Cycle tally of round-0: LDS pipe ~73k cyc/CU (45%) was
// the top consumer (ds_read 49k + shuffles 12k + stage-writes 12k), with 16
// barriers/block convoying all waves into LDS-burst-then-idle lockstep, and
// 4x read amplification (every wave re-read the whole 16KB chunk).
// THIS version deletes the LDS stage entirely: w2c is 2MB, massively L2-reused
// (128 row-blocks per f-group share each 256KB slice), so B fragments are read
// DIRECTLY from global into MFMA operand VGPRs. Wave split changes to
// 2 row-halves x 2 h-halves: each wave owns 32 rows x 64 h, reads 8KB B/phase
// (half of before; aggregate 0.54GB ~ 13 TB/s from L2, under the 34.5 ceiling).
// Removes: all 16 K-loop barriers, all B ds_reads, all staging. MFMA count
// unchanged. LN mean/var now crosses the h-split: 1KB LDS exchange + 2
// barriers per f (8 total). Regs: acc 64 + A 32 + out_acc 32 ~ same tier.
__global__ __launch_bounds__(256, 3) void k_main(
    const _Float16* __restrict__ w2c,   // [32][4][4][256][8] fp16 chunks
    const float* __restrict__ x_t,      // [32][8192]
    const float* __restrict__ wts_t,    // [32][8192]
    const float* __restrict__ fc1w, const float* __restrict__ fc1b,
    const float* __restrict__ fc2b,
    const float* __restrict__ skw, const float* __restrict__ skb,
    const float* __restrict__ lng, const float* __restrict__ lnb,
    float* __restrict__ out)            // [8192][128], zeroed by k_prep
{
    // [rowhalf][rg_grp][q][rg][hhalf][s|sq]
    __shared__ float red[2][2][4][4][2][2];

    const int tid = threadIdx.x;
    const int fbase = (blockIdx.x >> 7) * 4;
    const int row0 = (blockIdx.x & 127) * 64;

    const int lane = tid & 63;
    const int wv = tid >> 6;
    const int rowhalf = wv >> 1;        // which 32-row half of the block
    const int hhalf = wv & 1;           // which 64-h half of the output
    const int l15 = lane & 15;
    const int q = lane >> 4;

    float out_acc[2][4][4];
    #pragma unroll
    for (int g2 = 0; g2 < 2; ++g2)
        #pragma unroll
        for (int nt = 0; nt < 4; ++nt)
            #pragma unroll
            for (int rg = 0; rg < 4; ++rg) out_acc[g2][nt][rg] = 0.f;

    for (int fi = 0; fi < 4; ++fi) {
        const int f = fbase + fi;
        const float* xcol = x_t + (size_t)f * 8192 + row0 + rowhalf * 32;
        const float* wcol = wts_t + (size_t)f * 8192 + row0 + rowhalf * 32;
        const float xv0 = xcol[l15];
        const float xv1 = xcol[16 + l15];

        // A-frags for both row-groups, all 4 kq (proven layout from round-12)
        half8 A0[4], A1[4];
        #pragma unroll
        for (int kq = 0; kq < 4; ++kq) {
            const float* wp = fc1w + f * 128 + kq * 32 + 8 * q;
            const float* bp = fc1b + f * 128 + kq * 32 + 8 * q;
            f4 w0 = *(const f4*)wp, w1v = *(const f4*)(wp + 4);
            f4 b0 = *(const f4*)bp, b1v = *(const f4*)(bp + 4);
            #pragma unroll
            for (int j = 0; j < 4; ++j) {
                A0[kq][j]     = (_Float16)felu(fmaf(xv0, w0[j], b0[j]));
                A0[kq][4 + j] = (_Float16)felu(fmaf(xv0, w1v[j], b1v[j]));
                A1[kq][j]     = (_Float16)felu(fmaf(xv1, w0[j], b0[j]));
                A1[kq][4 + j] = (_Float16)felu(fmaf(xv1, w1v[j], b1v[j]));
            }
        }

        // bias-fold acc init (a and gate), both row-groups
        f4 accA0[4], accG0[4], accA1[4], accG1[4];
        #pragma unroll
        for (int nt = 0; nt < 4; ++nt) {
            const int h = hhalf * 64 + nt * 16 + l15;
            float ba = fc2b[f * 256 + h];
            float bg = fc2b[f * 256 + 128 + h];
            #pragma unroll
            for (int rg = 0; rg < 4; ++rg) {
                accA0[nt][rg] = ba; accA1[nt][rg] = ba;
                accG0[nt][rg] = bg; accG1[nt][rg] = bg;
            }
        }

        // per-lane B base: chunk [f*4+kq][q][g][j8]; this lane's a-tile row
        const _Float16* bp0 = w2c + (size_t)f * 4 * 8192
                            + q * 2048 + hhalf * 512 + l15 * 8;

        #pragma unroll
        for (int kq = 0; kq < 4; ++kq) {
            const _Float16* bp = bp0 + kq * 8192;
            // a-tiles (g = h)
            half8 B0 = *(const half8*)(bp);
            half8 B1 = *(const half8*)(bp + 128);
            half8 B2 = *(const half8*)(bp + 256);
            half8 B3 = *(const half8*)(bp + 384);
            accA0[0] = __builtin_amdgcn_mfma_f32_16x16x32_f16(A0[kq], B0, accA0[0], 0, 0, 0);
            accA1[0] = __builtin_amdgcn_mfma_f32_16x16x32_f16(A1[kq], B0, accA1[0], 0, 0, 0);
            accA0[1] = __builtin_amdgcn_mfma_f32_16x16x32_f16(A0[kq], B1, accA0[1], 0, 0, 0);
            accA1[1] = __builtin_amdgcn_mfma_f32_16x16x32_f16(A1[kq], B1, accA1[1], 0, 0, 0);
            accA0[2] = __builtin_amdgcn_mfma_f32_16x16x32_f16(A0[kq], B2, accA0[2], 0, 0, 0);
            accA1[2] = __builtin_amdgcn_mfma_f32_16x16x32_f16(A1[kq], B2, accA1[2], 0, 0, 0);
            accA0[3] = __builtin_amdgcn_mfma_f32_16x16x32_f16(A0[kq], B3, accA0[3], 0, 0, 0);
            accA1[3] = __builtin_amdgcn_mfma_f32_16x16x32_f16(A1[kq], B3, accA1[3], 0, 0, 0);
            // gate tiles (g = 128 + h)
            half8 G0 = *(const half8*)(bp + 1024);
            half8 G1 = *(const half8*)(bp + 1152);
            half8 G2 = *(const half8*)(bp + 1280);
            half8 G3 = *(const half8*)(bp + 1408);
            accG0[0] = __builtin_amdgcn_mfma_f32_16x16x32_f16(A0[kq], G0, accG0[0], 0, 0, 0);
            accG1[0] = __builtin_amdgcn_mfma_f32_16x16x32_f16(A1[kq], G0, accG1[0], 0, 0, 0);
            accG0[1] = __builtin_amdgcn_mfma_f32_16x16x32_f16(A0[kq], G1, accG0[1], 0, 0, 0);
            accG1[1] = __builtin_amdgcn_mfma_f32_16x16x32_f16(A1[kq], G1, accG1[1], 0, 0, 0);
            accG0[2] = __builtin_amdgcn_mfma_f32_16x16x32_f16(A0[kq], G2, accG0[2], 0, 0, 0);
            accG1[2] = __builtin_amdgcn_mfma_f32_16x16x32_f16(A1[kq], G2, accG1[2], 0, 0, 0);
            accG0[3] = __builtin_amdgcn_mfma_f32_16x16x32_f16(A0[kq], G3, accG0[3], 0, 0, 0);
            accG1[3] = __builtin_amdgcn_mfma_f32_16x16x32_f16(A1[kq], G3, accG1[3], 0, 0, 0);
        }

        // ---- epilogue: GLU + skip, partial (64-h) sums, cross-wave LN ----
        float s0[4], sq0[4], s1[4], sq1[4];
        #pragma unroll
        for (int rg = 0; rg < 4; ++rg) { s0[rg] = 0.f; sq0[rg] = 0.f; s1[rg] = 0.f; sq1[rg] = 0.f; }

        f4 xr0 = *(const f4*)(xcol + 4 * q);
        f4 xr1 = *(const f4*)(xcol + 16 + 4 * q);
        #pragma unroll
        for (int nt = 0; nt < 4; ++nt) {
            const int h = hhalf * 64 + nt * 16 + l15;
            float sw = skw[f * 128 + h];
            float sb = skb[f * 128 + h];
            #pragma unroll
            for (int rg = 0; rg < 4; ++rg) {
                float v0 = fmaf(xr0[rg], sw, sb) + accA0[nt][rg] * fsig(accG0[nt][rg]);
                float v1 = fmaf(xr1[rg], sw, sb) + accA1[nt][rg] * fsig(accG1[nt][rg]);
                accA0[nt][rg] = v0;
                accA1[nt][rg] = v1;
                s0[rg] += v0; sq0[rg] = fmaf(v0, v0, sq0[rg]);
                s1[rg] += v1; sq1[rg] = fmaf(v1, v1, sq1[rg]);
            }
        }
        #pragma unroll
        for (int o = 1; o < 16; o <<= 1) {
            #pragma unroll
            for (int rg = 0; rg < 4; ++rg) {
                s0[rg] += __shfl_xor(s0[rg], o, 64);
                sq0[rg] += __shfl_xor(sq0[rg], o, 64);
                s1[rg] += __shfl_xor(s1[rg], o, 64);
                sq1[rg] += __shfl_xor(sq1[rg], o, 64);
            }
        }
        if (l15 == 0) {
            #pragma unroll
            for (int rg = 0; rg < 4; ++rg) {
                red[rowhalf][0][q][rg][hhalf][0] = s0[rg];
                red[rowhalf][0][q][rg][hhalf][1] = sq0[rg];
                red[rowhalf][1][q][rg][hhalf][0] = s1[rg];
                red[rowhalf][1][q][rg][hhalf][1] = sq1[rg];
            }
        }
        __syncthreads();

        f4 wr0 = *(const f4*)(wcol + 4 * q);
        f4 wr1 = *(const f4*)(wcol + 16 + 4 * q);
        float mu0[4], c10[4], mu1[4], c11[4];
        #pragma unroll
        for (int rg = 0; rg < 4; ++rg) {
            float st0 = s0[rg] + red[rowhalf][0][q][rg][hhalf ^ 1][0];
            float qt0 = sq0[rg] + red[rowhalf][0][q][rg][hhalf ^ 1][1];
            float st1 = s1[rg] + red[rowhalf][1][q][rg][hhalf ^ 1][0];
            float qt1 = sq1[rg] + red[rowhalf][1][q][rg][hhalf ^ 1][1];
            mu0[rg] = st0 * (1.f / 128.f);
            mu1[rg] = st1 * (1.f / 128.f);
            float var0 = qt0 * (1.f / 128.f) - mu0[rg] * mu0[rg];
            float var1 = qt1 * (1.f / 128.f) - mu1[rg] * mu1[rg];
            c10[rg] = wr0[rg] * frsq(fmaxf(var0, 0.f) + EPS);
            c11[rg] = wr1[rg] * frsq(fmaxf(var1, 0.f) + EPS);
        }
        #pragma unroll
        for (int nt = 0; nt < 4; ++nt) {
            const int h = hhalf * 64 + nt * 16 + l15;
            float lg = lng[f * 128 + h];
            float lb = lnb[f * 128 + h];
            #pragma unroll
            for (int rg = 0; rg < 4; ++rg) {
                float u0 = (accA0[nt][rg] - mu0[rg]) * c10[rg];
                float u1 = (accA1[nt][rg] - mu1[rg]) * c11[rg];
                out_acc[0][nt][rg] = fmaf(u0, lg, fmaf(wr0[rg], lb, out_acc[0][nt][rg]));
                out_acc[1][nt][rg] = fmaf(u1, lg, fmaf(wr1[rg], lb, out_acc[1][nt][rg]));
            }
        }
        __syncthreads();   // red[] safe to overwrite next f
    }

    // ---- single atomic combine pass (8 partial adds per element total) ----
    #pragma unroll
    for (int g2 = 0; g2 < 2; ++g2) {
        #pragma unroll
        for (int nt = 0; nt < 4; ++nt) {
            #pragma unroll
            for (int rg = 0; rg < 4; ++rg) {
                const int r = row0 + rowhalf * 32 + g2 * 16 + 4 * q + rg;
                atomicAdd(&out[(size_t)r * 128 + hhalf * 64 + nt * 16 + l15],
                          out_acc[g2][nt][rg]);
            }
        }
    }
}

extern "C" void kernel_launch(void* const* d_in, const int* in_sizes, int n_in,
                              void* d_out, int out_size, void* d_ws, size_t ws_size,
                              hipStream_t stream) {
    const float* x     = (const float*)d_in[0];
    const float* wg1w  = (const float*)d_in[1];
    const float* wg1b  = (const float*)d_in[2];
    const float* wg2w  = (const float*)d_in[3];
    const float* wg2b  = (const float*)d_in[4];
    const float* wglng = (const float*)d_in[5];
    const float* wglnb = (const float*)d_in[6];
    const float* fc1w  = (const float*)d_in[7];
    const float* fc1b  = (const float*)d_in[8];
    const float* fc2w  = (const float*)d_in[9];
    const float* fc2b  = (const float*)d_in[10];
    const float* skw   = (const float*)d_in[11];
    const float* skb   = (const float*)d_in[12];
    const float* lng   = (const float*)d_in[13];
    const float* lnb   = (const float*)d_in[14];
    float* out = (float*)d_out;

    char* ws = (char*)d_ws;
    _Float16* w2c = (_Float16*)ws;               // 2 MB chunked fp16 W2
    float* x_t    = (float*)(ws + (2u << 20));   // 1 MB x transposed [f][row]
    float* wts_t  = (float*)(ws + (3u << 20));   // 1 MB weights transposed

    k_prep<<<dim3(784), dim3(256), 0, stream>>>(fc2w, w2c, x, wg1w, wg1b,
                                                wg2w, wg2b, wglng, wglnb,
                                                x_t, wts_t, out);
    k_main<<<dim3(1024), dim3(256), 0, stream>>>(w2c, x_t, wts_t, fc1w, fc1b,
                                                 fc2b, skw, skb, lng, lnb, out);
}

// Round 4
// 175.438 us; speedup vs baseline: 1.0212x; 1.0212x over previous
//
#include <hip/hip_runtime.h>
#include <cstdint>
#include <cstddef>

#define EPS 1e-5f

typedef float    f4    __attribute__((ext_vector_type(4)));
typedef _Float16 half8 __attribute__((ext_vector_type(8)));

#define S_XS 33
#define LOG2E 1.44269504088896f

#define GLD_LDS16(gp, lp)                                        \
    __builtin_amdgcn_global_load_lds(                            \
        (const __attribute__((address_space(1))) void*)(gp),     \
        (__attribute__((address_space(3))) void*)(lp), 16, 0, 0)

// raw-rate transcendentals (v_exp_f32 / v_rcp_f32 / v_rsq_f32)
__device__ __forceinline__ float fexp(float x)  { return __builtin_amdgcn_exp2f(x * LOG2E); }
__device__ __forceinline__ float frcp(float x)  { return __builtin_amdgcn_rcpf(x); }
__device__ __forceinline__ float frsq(float x)  { return __builtin_amdgcn_rsqf(x); }
__device__ __forceinline__ float fsig(float g)  { return frcp(1.f + __builtin_amdgcn_exp2f(g * -LOG2E)); }
__device__ __forceinline__ float felu(float t)  { return t > 0.f ? t : fexp(t) - 1.f; }

// ---- K_prep: conv (0..511) + weight-GRN (512..767) + out-zero (768..783) ----
// UNCHANGED from the proven 164.5 µs version.
__global__ __launch_bounds__(256) void k_prep(
    const float* __restrict__ in_w2, _Float16* __restrict__ w2c,
    const float* __restrict__ x, const float* __restrict__ w1,
    const float* __restrict__ b1, const float* __restrict__ w2,
    const float* __restrict__ b2, const float* __restrict__ lng,
    const float* __restrict__ lnb,
    float* __restrict__ x_t, float* __restrict__ wts_t,
    float* __restrict__ outp)
{
    __shared__ float w1s[32 * S_XS];
    __shared__ float w2s[64 * S_XS];
    __shared__ float xsW[32 * S_XS];
    __shared__ float ytile[32 * S_XS];

    const int bid = blockIdx.x;
    const int tid = threadIdx.x;

    if (bid < 512) {   // ---- conv path ----
        int t = bid * 256 + tid;
        int q  = t & 3;
        int g  = (t >> 2) & 255;
        int fk = t >> 10;                   // f*4 + kq
        int f = fk >> 2, kq = fk & 3;
        const float* ip = in_w2 + ((size_t)f * 256 + g) * 128 + kq * 32 + q * 8;
        f4 v0 = *(const f4*)ip, v1 = *(const f4*)(ip + 4);
        half8 h;
        #pragma unroll
        for (int i = 0; i < 4; ++i) { h[i] = (_Float16)v0[i]; h[4 + i] = (_Float16)v1[i]; }
        *(half8*)(w2c + (size_t)fk * 8192 + q * 2048 + g * 8) = h;
        return;
    }

    if (bid >= 768) {  // ---- out-zero path (replaces memset launch) ----
        int t = (bid - 768) * 256 + tid;
        f4 z; z[0] = 0.f; z[1] = 0.f; z[2] = 0.f; z[3] = 0.f;
        for (int i = t; i < 262144; i += 4096)
            *(f4*)(outp + (size_t)i * 4) = z;
        return;
    }

    // ---- weight-GRN path ----
    const int lane = tid & 63;
    const int f = lane & 31;
    const int wv = tid >> 6;
    const int row0 = (bid - 512) * 32;

    for (int i = tid; i < 1024; i += 256) {
        int r = i >> 5, c = i & 31;
        w1s[r * S_XS + c] = w1[i];
        xsW[r * S_XS + c] = x[(size_t)row0 * 32 + i];
    }
    for (int i = tid; i < 2048; i += 256) {
        int r = i >> 5, c = i & 31;
        w2s[r * S_XS + c] = w2[i];
    }
    const float b1f = b1[f], b2a = b2[f], b2g = b2[f + 32];
    const float lgf = lng[f], lbf = lnb[f];
    __syncthreads();

    for (int rr = 0; rr < 8; ++rr) {
        const int r = wv * 8 + rr;
        float acc = b1f;
        #pragma unroll
        for (int k = 0; k < 32; ++k)
            acc = fmaf(w1s[f * S_XS + k], xsW[r * S_XS + k], acc);
        float hval = felu(acc);

        float a = b2a, g = b2g;
        #pragma unroll
        for (int k = 0; k < 32; ++k) {
            float hk = __shfl(hval, k, 64);
            a = fmaf(w2s[f * S_XS + k], hk, a);
            g = fmaf(w2s[(f + 32) * S_XS + k], hk, g);
        }
        float xv = xsW[r * S_XS + f];
        float v = xv + a * fsig(g);

        float s = v;
        #pragma unroll
        for (int o = 1; o < 64; o <<= 1) s += __shfl_xor(s, o, 64);
        float mu = s * (1.f / 64.f);
        float d = v - mu;
        float sq = d * d;
        #pragma unroll
        for (int o = 1; o < 64; o <<= 1) sq += __shfl_xor(sq, o, 64);
        float y = d * frsq(sq * (1.f / 64.f) + EPS) * lgf + lbf;

        float m = y;
        #pragma unroll
        for (int o = 1; o < 64; o <<= 1) m = fmaxf(m, __shfl_xor(m, o, 64));
        float e = fexp(y - m);
        float se = e;
        #pragma unroll
        for (int o = 1; o < 64; o <<= 1) se += __shfl_xor(se, o, 64);
        if (lane < 32) ytile[r * S_XS + f] = e * 2.f * frcp(se);
    }
    __syncthreads();
    for (int i = tid; i < 1024; i += 256) {
        int ff = i >> 5, r = i & 31;
        x_t[(size_t)ff * 8192 + row0 + r]   = xsW[r * S_XS + ff];
        wts_t[(size_t)ff * 8192 + row0 + r] = ytile[r * S_XS + ff];
    }
}

// ---------------- K_main v4: round-0 staging + 2x B-frag register reuse ------
// Evidence so far: r1 (deeper pipeline) REGRESSED 66.5->85; r2 (no LDS, B
// direct from L2) REGRESSED 66.5->82. Round-0 structure is the proven best
// delivery mechanism; its top pipe consumer is ds_read (~49k cyc/CU of 160k),
// carrying a 4x amplification (each of 4 waves reads the whole 16KB chunk).
// THIS version keeps round-0's staging/dbuf/barrier skeleton VERBATIM and
// changes ONE thing: wave split 4x(16 rows x 256 g) -> 2 rowhalf x 2 hhalf
// (32 rows x 128 g each). Per kq phase a wave loads 8 B-frags (its half of
// the chunk) and reuses each across its two row-group MFMAs: 16 MFMA/phase
// unchanged, ds_read_b128 16 -> 8 per wave (block: 64KB -> 32KB per chunk).
// LN mean/var crosses the h-split: red[] LDS exchange (1KB, 2 barriers/f),
// taken verbatim from r2 which passed correctness with this exact split.
// Regs: +16 VGPR (second A-frag set) -> ~100 arch + 64 acc, same 3-wave tier.
__global__ __launch_bounds__(256, 3) void k_main(
    const _Float16* __restrict__ w2c,   // [32][4][4][256][8] fp16 chunks
    const float* __restrict__ x_t,      // [32][8192]
    const float* __restrict__ wts_t,    // [32][8192]
    const float* __restrict__ fc1w, const float* __restrict__ fc1b,
    const float* __restrict__ fc2b,
    const float* __restrict__ skw, const float* __restrict__ skb,
    const float* __restrict__ lng, const float* __restrict__ lnb,
    float* __restrict__ out)            // [8192][128], zeroed by k_prep
{
    __shared__ __align__(16) _Float16 bchunk[2][8192];   // 32 KB dbuf
    __shared__ float red[2][2][4][4][2][2];  // [rowhalf][rowgrp][q][rg][hhalf][s|sq]

    const int tid = threadIdx.x;
    const int fbase = (blockIdx.x >> 7) * 4;
    const int row0 = (blockIdx.x & 127) * 64;

    const int lane = tid & 63;
    const int wv = tid >> 6;
    const int rowhalf = wv >> 1;        // which 32-row half of the block
    const int hhalf = wv & 1;           // which 64-h half of the output
    const int l15 = lane & 15;
    const int q = lane >> 4;
    // B-frag base within a chunk (halves): this wave's h-half
    const int boff = q * 2048 + hhalf * 512 + l15 * 8;

    auto stage = [&](int c) {
        const _Float16* gp = w2c + ((size_t)(fbase + (c >> 2)) * 4 + (c & 3)) * 8192;
        #pragma unroll
        for (int r = 0; r < 4; ++r)
            GLD_LDS16(gp + (r * 256 + tid) * 8,
                      &bchunk[c & 1][(r * 256 + tid) * 8]);
    };

    float out_acc[2][4][4];
    #pragma unroll
    for (int g2 = 0; g2 < 2; ++g2)
        #pragma unroll
        for (int nt = 0; nt < 4; ++nt)
            #pragma unroll
            for (int rg = 0; rg < 4; ++rg) out_acc[g2][nt][rg] = 0.f;

    stage(0);
    __syncthreads();   // chunk 0 resident

    int c = 0;
    for (int fi = 0; fi < 4; ++fi) {
        const int f = fbase + fi;
        const float* xcol = x_t + (size_t)f * 8192 + row0 + rowhalf * 32;
        const float* wcol = wts_t + (size_t)f * 8192 + row0 + rowhalf * 32;
        const float xv0 = xcol[l15];
        const float xv1 = xcol[16 + l15];

        // A-frags for both row-groups, all 4 kq (round-12 layout)
        half8 A0[4], A1[4];
        #pragma unroll
        for (int kq = 0; kq < 4; ++kq) {
            const float* wp = fc1w + f * 128 + kq * 32 + 8 * q;
            const float* bp = fc1b + f * 128 + kq * 32 + 8 * q;
            f4 w0 = *(const f4*)wp, w1v = *(const f4*)(wp + 4);
            f4 b0 = *(const f4*)bp, b1v = *(const f4*)(bp + 4);
            #pragma unroll
            for (int j = 0; j < 4; ++j) {
                A0[kq][j]     = (_Float16)felu(fmaf(xv0, w0[j], b0[j]));
                A0[kq][4 + j] = (_Float16)felu(fmaf(xv0, w1v[j], b1v[j]));
                A1[kq][j]     = (_Float16)felu(fmaf(xv1, w0[j], b0[j]));
                A1[kq][4 + j] = (_Float16)felu(fmaf(xv1, w1v[j], b1v[j]));
            }
        }

        // bias-fold acc init (a and gate), both row-groups
        f4 accA0[4], accG0[4], accA1[4], accG1[4];
        #pragma unroll
        for (int nt = 0; nt < 4; ++nt) {
            const int h = hhalf * 64 + nt * 16 + l15;
            float ba = fc2b[f * 256 + h];
            float bg = fc2b[f * 256 + 128 + h];
            #pragma unroll
            for (int rg = 0; rg < 4; ++rg) {
                accA0[nt][rg] = ba; accA1[nt][rg] = ba;
                accG0[nt][rg] = bg; accG1[nt][rg] = bg;
            }
        }

        #pragma unroll
        for (int kq = 0; kq < 4; ++kq, ++c) {
            if (c + 1 < 16) stage(c + 1);
            const _Float16* bb = &bchunk[c & 1][boff];
            // 8 ds_read_b128, each feeding 2 MFMAs (row-groups 0 and 1)
            #pragma unroll
            for (int nt = 0; nt < 4; ++nt) {
                half8 B = *(const half8*)(bb + nt * 128);          // a-tile
                accA0[nt] = __builtin_amdgcn_mfma_f32_16x16x32_f16(A0[kq], B, accA0[nt], 0, 0, 0);
                accA1[nt] = __builtin_amdgcn_mfma_f32_16x16x32_f16(A1[kq], B, accA1[nt], 0, 0, 0);
                half8 G = *(const half8*)(bb + 1024 + nt * 128);   // gate tile
                accG0[nt] = __builtin_amdgcn_mfma_f32_16x16x32_f16(A0[kq], G, accG0[nt], 0, 0, 0);
                accG1[nt] = __builtin_amdgcn_mfma_f32_16x16x32_f16(A1[kq], G, accG1[nt], 0, 0, 0);
            }
            __syncthreads();   // chunk c consumed everywhere; stage(c+1) drained
        }

        // ---- epilogue: GLU + skip, partial (64-h) sums, cross-wave LN ----
        float s0[4], sq0[4], s1[4], sq1[4];
        #pragma unroll
        for (int rg = 0; rg < 4; ++rg) { s0[rg] = 0.f; sq0[rg] = 0.f; s1[rg] = 0.f; sq1[rg] = 0.f; }

        f4 xr0 = *(const f4*)(xcol + 4 * q);
        f4 xr1 = *(const f4*)(xcol + 16 + 4 * q);
        #pragma unroll
        for (int nt = 0; nt < 4; ++nt) {
            const int h = hhalf * 64 + nt * 16 + l15;
            float sw = skw[f * 128 + h];
            float sb = skb[f * 128 + h];
            #pragma unroll
            for (int rg = 0; rg < 4; ++rg) {
                float v0 = fmaf(xr0[rg], sw, sb) + accA0[nt][rg] * fsig(accG0[nt][rg]);
                float v1 = fmaf(xr1[rg], sw, sb) + accA1[nt][rg] * fsig(accG1[nt][rg]);
                accA0[nt][rg] = v0;
                accA1[nt][rg] = v1;
                s0[rg] += v0; sq0[rg] = fmaf(v0, v0, sq0[rg]);
                s1[rg] += v1; sq1[rg] = fmaf(v1, v1, sq1[rg]);
            }
        }
        #pragma unroll
        for (int o = 1; o < 16; o <<= 1) {
            #pragma unroll
            for (int rg = 0; rg < 4; ++rg) {
                s0[rg] += __shfl_xor(s0[rg], o, 64);
                sq0[rg] += __shfl_xor(sq0[rg], o, 64);
                s1[rg] += __shfl_xor(s1[rg], o, 64);
                sq1[rg] += __shfl_xor(sq1[rg], o, 64);
            }
        }
        if (l15 == 0) {
            #pragma unroll
            for (int rg = 0; rg < 4; ++rg) {
                red[rowhalf][0][q][rg][hhalf][0] = s0[rg];
                red[rowhalf][0][q][rg][hhalf][1] = sq0[rg];
                red[rowhalf][1][q][rg][hhalf][0] = s1[rg];
                red[rowhalf][1][q][rg][hhalf][1] = sq1[rg];
            }
        }
        __syncthreads();

        f4 wr0 = *(const f4*)(wcol + 4 * q);
        f4 wr1 = *(const f4*)(wcol + 16 + 4 * q);
        float mu0[4], c10[4], mu1[4], c11[4];
        #pragma unroll
        for (int rg = 0; rg < 4; ++rg) {
            float st0 = s0[rg] + red[rowhalf][0][q][rg][hhalf ^ 1][0];
            float qt0 = sq0[rg] + red[rowhalf][0][q][rg][hhalf ^ 1][1];
            float st1 = s1[rg] + red[rowhalf][1][q][rg][hhalf ^ 1][0];
            float qt1 = sq1[rg] + red[rowhalf][1][q][rg][hhalf ^ 1][1];
            mu0[rg] = st0 * (1.f / 128.f);
            mu1[rg] = st1 * (1.f / 128.f);
            float var0 = qt0 * (1.f / 128.f) - mu0[rg] * mu0[rg];
            float var1 = qt1 * (1.f / 128.f) - mu1[rg] * mu1[rg];
            c10[rg] = wr0[rg] * frsq(fmaxf(var0, 0.f) + EPS);
            c11[rg] = wr1[rg] * frsq(fmaxf(var1, 0.f) + EPS);
        }
        #pragma unroll
        for (int nt = 0; nt < 4; ++nt) {
            const int h = hhalf * 64 + nt * 16 + l15;
            float lg = lng[f * 128 + h];
            float lb = lnb[f * 128 + h];
            #pragma unroll
            for (int rg = 0; rg < 4; ++rg) {
                float u0 = (accA0[nt][rg] - mu0[rg]) * c10[rg];
                float u1 = (accA1[nt][rg] - mu1[rg]) * c11[rg];
                out_acc[0][nt][rg] = fmaf(u0, lg, fmaf(wr0[rg], lb, out_acc[0][nt][rg]));
                out_acc[1][nt][rg] = fmaf(u1, lg, fmaf(wr1[rg], lb, out_acc[1][nt][rg]));
            }
        }
        __syncthreads();   // red[] safe to overwrite next f
    }

    // ---- single atomic combine pass (8 partial adds per element total) ----
    #pragma unroll
    for (int g2 = 0; g2 < 2; ++g2) {
        #pragma unroll
        for (int nt = 0; nt < 4; ++nt) {
            #pragma unroll
            for (int rg = 0; rg < 4; ++rg) {
                const int r = row0 + rowhalf * 32 + g2 * 16 + 4 * q + rg;
                atomicAdd(&out[(size_t)r * 128 + hhalf * 64 + nt * 16 + l15],
                          out_acc[g2][nt][rg]);
            }
        }
    }
}

extern "C" void kernel_launch(void* const* d_in, const int* in_sizes, int n_in,
                              void* d_out, int out_size, void* d_ws, size_t ws_size,
                              hipStream_t stream) {
    const float* x     = (const float*)d_in[0];
    const float* wg1w  = (const float*)d_in[1];
    const float* wg1b  = (const float*)d_in[2];
    const float* wg2w  = (const float*)d_in[3];
    const float* wg2b  = (const float*)d_in[4];
    const float* wglng = (const float*)d_in[5];
    const float* wglnb = (const float*)d_in[6];
    const float* fc1w  = (const float*)d_in[7];
    const float* fc1b  = (const float*)d_in[8];
    const float* fc2w  = (const float*)d_in[9];
    const float* fc2b  = (const float*)d_in[10];
    const float* skw   = (const float*)d_in[11];
    const float* skb   = (const float*)d_in[12];
    const float* lng   = (const float*)d_in[13];
    const float* lnb   = (const float*)d_in[14];
    float* out = (float*)d_out;

    char* ws = (char*)d_ws;
    _Float16* w2c = (_Float16*)ws;               // 2 MB chunked fp16 W2
    float* x_t    = (float*)(ws + (2u << 20));   // 1 MB x transposed [f][row]
    float* wts_t  = (float*)(ws + (3u << 20));   // 1 MB weights transposed

    k_prep<<<dim3(784), dim3(256), 0, stream>>>(fc2w, w2c, x, wg1w, wg1b,
                                                wg2w, wg2b, wglng, wglnb,
                                                x_t, wts_t, out);
    k_main<<<dim3(1024), dim3(256), 0, stream>>>(w2c, x_t, wts_t, fc1w, fc1b,
                                                 fc2b, skw, skb, lng, lnb, out);
}

// Round 6
// 165.673 us; speedup vs baseline: 1.0814x; 1.0589x over previous
//
#include <hip/hip_runtime.h>
#include <cstdint>
#include <cstddef>

#define EPS 1e-5f

typedef float    f4    __attribute__((ext_vector_type(4)));
typedef _Float16 half8 __attribute__((ext_vector_type(8)));
typedef _Float16 half4 __attribute__((ext_vector_type(4)));

#define S_XS 33
#define LOG2E 1.44269504088896f

#define GLD_LDS16(gp, lp)                                        \
    __builtin_amdgcn_global_load_lds(                            \
        (const __attribute__((address_space(1))) void*)(gp),     \
        (__attribute__((address_space(3))) void*)(lp), 16, 0, 0)

// raw-rate transcendentals (v_exp_f32 / v_rcp_f32 / v_rsq_f32)
__device__ __forceinline__ float fexp(float x)  { return __builtin_amdgcn_exp2f(x * LOG2E); }
__device__ __forceinline__ float frcp(float x)  { return __builtin_amdgcn_rcpf(x); }
__device__ __forceinline__ float frsq(float x)  { return __builtin_amdgcn_rsqf(x); }
__device__ __forceinline__ float fsig(float g)  { return frcp(1.f + __builtin_amdgcn_exp2f(g * -LOG2E)); }
__device__ __forceinline__ float felu(float t)  { return t > 0.f ? t : fexp(t) - 1.f; }

// ---- K_prep: conv (0..511) + weight-GRN (512..767) + out-zero (768..783) ----
// conv: f_fc2_w fp32 -> fp16, chunk layout [f][kq][q][g][j8] (16 KB per (f,kq)).
// out-zero path (proven rounds 13/14) replaces the hipMemsetAsync dispatch.
__global__ __launch_bounds__(256) void k_prep(
    const float* __restrict__ in_w2, _Float16* __restrict__ w2c,
    const float* __restrict__ x, const float* __restrict__ w1,
    const float* __restrict__ b1, const float* __restrict__ w2,
    const float* __restrict__ b2, const float* __restrict__ lng,
    const float* __restrict__ lnb,
    float* __restrict__ x_t, float* __restrict__ wts_t,
    float* __restrict__ outp)
{
    __shared__ float w1s[32 * S_XS];
    __shared__ float w2s[64 * S_XS];
    __shared__ float xsW[32 * S_XS];
    __shared__ float ytile[32 * S_XS];

    const int bid = blockIdx.x;
    const int tid = threadIdx.x;

    if (bid < 512) {   // ---- conv path ----
        int t = bid * 256 + tid;
        int q  = t & 3;
        int g  = (t >> 2) & 255;
        int fk = t >> 10;                   // f*4 + kq
        int f = fk >> 2, kq = fk & 3;
        const float* ip = in_w2 + ((size_t)f * 256 + g) * 128 + kq * 32 + q * 8;
        f4 v0 = *(const f4*)ip, v1 = *(const f4*)(ip + 4);
        half8 h;
        #pragma unroll
        for (int i = 0; i < 4; ++i) { h[i] = (_Float16)v0[i]; h[4 + i] = (_Float16)v1[i]; }
        *(half8*)(w2c + (size_t)fk * 8192 + q * 2048 + g * 8) = h;
        return;
    }

    if (bid >= 768) {  // ---- out-zero path (replaces memset launch) ----
        int t = (bid - 768) * 256 + tid;
        f4 z; z[0] = 0.f; z[1] = 0.f; z[2] = 0.f; z[3] = 0.f;
        for (int i = t; i < 262144; i += 4096)
            *(f4*)(outp + (size_t)i * 4) = z;
        return;
    }

    // ---- weight-GRN path ----
    const int lane = tid & 63;
    const int f = lane & 31;
    const int wv = tid >> 6;
    const int row0 = (bid - 512) * 32;

    for (int i = tid; i < 1024; i += 256) {
        int r = i >> 5, c = i & 31;
        w1s[r * S_XS + c] = w1[i];
        xsW[r * S_XS + c] = x[(size_t)row0 * 32 + i];
    }
    for (int i = tid; i < 2048; i += 256) {
        int r = i >> 5, c = i & 31;
        w2s[r * S_XS + c] = w2[i];
    }
    const float b1f = b1[f], b2a = b2[f], b2g = b2[f + 32];
    const float lgf = lng[f], lbf = lnb[f];
    __syncthreads();

    for (int rr = 0; rr < 8; ++rr) {
        const int r = wv * 8 + rr;
        float acc = b1f;
        #pragma unroll
        for (int k = 0; k < 32; ++k)
            acc = fmaf(w1s[f * S_XS + k], xsW[r * S_XS + k], acc);
        float hval = felu(acc);

        float a = b2a, g = b2g;
        #pragma unroll
        for (int k = 0; k < 32; ++k) {
            float hk = __shfl(hval, k, 64);
            a = fmaf(w2s[f * S_XS + k], hk, a);
            g = fmaf(w2s[(f + 32) * S_XS + k], hk, g);
        }
        float xv = xsW[r * S_XS + f];
        float v = xv + a * fsig(g);

        float s = v;
        #pragma unroll
        for (int o = 1; o < 64; o <<= 1) s += __shfl_xor(s, o, 64);
        float mu = s * (1.f / 64.f);
        float d = v - mu;
        float sq = d * d;
        #pragma unroll
        for (int o = 1; o < 64; o <<= 1) sq += __shfl_xor(sq, o, 64);
        float y = d * frsq(sq * (1.f / 64.f) + EPS) * lgf + lbf;

        float m = y;
        #pragma unroll
        for (int o = 1; o < 64; o <<= 1) m = fmaxf(m, __shfl_xor(m, o, 64));
        float e = fexp(y - m);
        float se = e;
        #pragma unroll
        for (int o = 1; o < 64; o <<= 1) se += __shfl_xor(se, o, 64);
        if (lane < 32) ytile[r * S_XS + f] = e * 2.f * frcp(se);
    }
    __syncthreads();
    for (int i = tid; i < 1024; i += 256) {
        int ff = i >> 5, r = i & 31;
        x_t[(size_t)ff * 8192 + row0 + r]   = xsW[r * S_XS + ff];
        wts_t[(size_t)ff * 8192 + row0 + r] = ytile[r * S_XS + ff];
    }
}

// ---------------- K_main: round-12 verbatim (proven optimum of this structure) ----
// Block = 64 rows x 4 features; wave wv owns rows [16wv,16wv+16) x all 256 g.
// 16-KB chunk staging, dbuf, 16 barriers; A-frags hoisted to f-start; ba/bg
// folded into acc init; in-wave LN; register out_acc; one atomic pass.
// Operating point (hard-won): 32 KB LDS + VGPR 84 (+64 AGPR acc) -> 3 waves/
// SIMD. SESSION LOG (this session's falsified theories — do NOT retry):
//   r1/r5 counted-vmcnt 3-ring (2 variants): fail/85us — drain was not the stall
//   r2 no-LDS B-direct-from-L2: 82us — L2 load latency beats staged ds_read
//   r3 h-split halved ds_read within this skeleton: 84us — LDS was not the bound
// Cycle tally: LDS ~22us, VALU ~20us, MFMA ~2us of 66.5 — latency-bound sharp
// local optimum; perturbations of the instruction mix cost ~+17us each.
__global__ __launch_bounds__(256, 3) void k_main(
    const _Float16* __restrict__ w2c,   // [32][4][4][256][8] fp16 chunks
    const float* __restrict__ x_t,      // [32][8192]
    const float* __restrict__ wts_t,    // [32][8192]
    const float* __restrict__ fc1w, const float* __restrict__ fc1b,
    const float* __restrict__ fc2b,
    const float* __restrict__ skw, const float* __restrict__ skb,
    const float* __restrict__ lng, const float* __restrict__ lnb,
    float* __restrict__ out)            // [8192][128], zeroed by k_prep
{
    __shared__ __align__(16) _Float16 bchunk[2][8192];   // 32 KB total

    const int tid = threadIdx.x;
    const int fbase = (blockIdx.x >> 7) * 4;
    const int row0 = (blockIdx.x & 127) * 64;

    const int lane = tid & 63;
    const int wv = tid >> 6;
    const int l15 = lane & 15;
    const int q = lane >> 4;
    const int boff = q * 2048 + l15 * 8;   // swizzled B-frag base (halves)

    auto stage = [&](int c) {
        const _Float16* gp = w2c + ((size_t)(fbase + (c >> 2)) * 4 + (c & 3)) * 8192;
        #pragma unroll
        for (int r = 0; r < 4; ++r)
            GLD_LDS16(gp + (r * 256 + tid) * 8,
                      &bchunk[c & 1][(r * 256 + tid) * 8]);
    };

    float out_acc[8][4];
    #pragma unroll
    for (int nt = 0; nt < 8; ++nt)
        #pragma unroll
        for (int rg = 0; rg < 4; ++rg) out_acc[nt][rg] = 0.f;

    stage(0);
    __syncthreads();   // chunk 0 resident

    int c = 0;
    for (int fi = 0; fi < 4; ++fi) {
        const int f = fbase + fi;
        const float* xcol = x_t + (size_t)f * 8192 + row0 + wv * 16;
        const float* wcol = wts_t + (size_t)f * 8192 + row0 + wv * 16;
        const float xvA = xcol[l15];

        // A-frags for all 4 kq at f-start (proven rounds 9/12)
        half8 A[4];
        #pragma unroll
        for (int kq = 0; kq < 4; ++kq) {
            const float* wp = fc1w + f * 128 + kq * 32 + 8 * q;
            const float* bp = fc1b + f * 128 + kq * 32 + 8 * q;
            f4 w0 = *(const f4*)wp, w1v = *(const f4*)(wp + 4);
            f4 b0 = *(const f4*)bp, b1v = *(const f4*)(bp + 4);
            #pragma unroll
            for (int j = 0; j < 4; ++j) {
                A[kq][j]     = (_Float16)felu(fmaf(xvA, w0[j], b0[j]));
                A[kq][4 + j] = (_Float16)felu(fmaf(xvA, w1v[j], b1v[j]));
            }
        }

        // bias-fold: acc init from ba/bg (proven rounds 9/12)
        f4 acc[16];
        #pragma unroll
        for (int nt = 0; nt < 8; ++nt) {
            const int h = nt * 16 + l15;
            float ba = fc2b[f * 256 + h];
            float bg = fc2b[f * 256 + 128 + h];
            #pragma unroll
            for (int rg = 0; rg < 4; ++rg) { acc[nt][rg] = ba; acc[nt + 8][rg] = bg; }
        }

        #pragma unroll
        for (int kq = 0; kq < 4; ++kq, ++c) {
            if (c + 1 < 16) stage(c + 1);
            const _Float16* bb = &bchunk[c & 1][boff];
            #pragma unroll
            for (int nt = 0; nt < 16; ++nt) {
                half8 B = *(const half8*)(bb + nt * 128);   // [q][g=nt*16+l15][j]
                acc[nt] = __builtin_amdgcn_mfma_f32_16x16x32_f16(A[kq], B, acc[nt], 0, 0, 0);
            }
            __syncthreads();   // chunk c consumed everywhere; stage(c+1) drained
        }

        // ---- epilogue: round-12 verbatim ----
        f4 xr = *(const f4*)(xcol + 4 * q);
        f4 wr = *(const f4*)(wcol + 4 * q);
        float s[4] = {0.f, 0.f, 0.f, 0.f}, sq[4] = {0.f, 0.f, 0.f, 0.f};
        #pragma unroll
        for (int nt = 0; nt < 8; ++nt) {
            const int h = nt * 16 + l15;
            float sw = skw[f * 128 + h];
            float sb = skb[f * 128 + h];
            #pragma unroll
            for (int rg = 0; rg < 4; ++rg) {
                float a = acc[nt][rg];              // ba folded into init
                float g = acc[nt + 8][rg];          // bg folded into init
                float val = fmaf(xr[rg], sw, sb) + a * fsig(g);
                acc[nt][rg] = val;
                s[rg] += val;
                sq[rg] = fmaf(val, val, sq[rg]);
            }
        }
        #pragma unroll
        for (int o = 1; o < 16; o <<= 1) {
            #pragma unroll
            for (int rg = 0; rg < 4; ++rg) {
                s[rg] += __shfl_xor(s[rg], o, 64);
                sq[rg] += __shfl_xor(sq[rg], o, 64);
            }
        }
        float mu[4], c1[4];
        #pragma unroll
        for (int rg = 0; rg < 4; ++rg) {
            mu[rg] = s[rg] * (1.f / 128.f);
            float var = sq[rg] * (1.f / 128.f) - mu[rg] * mu[rg];
            c1[rg] = wr[rg] * frsq(fmaxf(var, 0.f) + EPS);
        }
        #pragma unroll
        for (int nt = 0; nt < 8; ++nt) {
            const int h = nt * 16 + l15;
            float lg = lng[f * 128 + h];
            float lb = lnb[f * 128 + h];
            #pragma unroll
            for (int rg = 0; rg < 4; ++rg) {
                float u = (acc[nt][rg] - mu[rg]) * c1[rg];
                out_acc[nt][rg] = fmaf(u, lg, fmaf(wr[rg], lb, out_acc[nt][rg]));
            }
        }
    }

    // ---- single atomic combine pass (8 partial adds per element total) ----
    #pragma unroll
    for (int nt = 0; nt < 8; ++nt) {
        #pragma unroll
        for (int rg = 0; rg < 4; ++rg) {
            const int r = row0 + wv * 16 + 4 * q + rg;
            atomicAdd(&out[(size_t)r * 128 + nt * 16 + l15], out_acc[nt][rg]);
        }
    }
}

extern "C" void kernel_launch(void* const* d_in, const int* in_sizes, int n_in,
                              void* d_out, int out_size, void* d_ws, size_t ws_size,
                              hipStream_t stream) {
    const float* x     = (const float*)d_in[0];
    const float* wg1w  = (const float*)d_in[1];
    const float* wg1b  = (const float*)d_in[2];
    const float* wg2w  = (const float*)d_in[3];
    const float* wg2b  = (const float*)d_in[4];
    const float* wglng = (const float*)d_in[5];
    const float* wglnb = (const float*)d_in[6];
    const float* fc1w  = (const float*)d_in[7];
    const float* fc1b  = (const float*)d_in[8];
    const float* fc2w  = (const float*)d_in[9];
    const float* fc2b  = (const float*)d_in[10];
    const float* skw   = (const float*)d_in[11];
    const float* skb   = (const float*)d_in[12];
    const float* lng   = (const float*)d_in[13];
    const float* lnb   = (const float*)d_in[14];
    float* out = (float*)d_out;

    char* ws = (char*)d_ws;
    _Float16* w2c = (_Float16*)ws;               // 2 MB chunked fp16 W2
    float* x_t    = (float*)(ws + (2u << 20));   // 1 MB x transposed [f][row]
    float* wts_t  = (float*)(ws + (3u << 20));   // 1 MB weights transposed

    k_prep<<<dim3(784), dim3(256), 0, stream>>>(fc2w, w2c, x, wg1w, wg1b,
                                                wg2w, wg2b, wglng, wglnb,
                                                x_t, wts_t, out);
    k_main<<<dim3(1024), dim3(256), 0, stream>>>(w2c, x_t, wts_t, fc1w, fc1b,
                                                 fc2b, skw, skb, lng, lnb, out);
}